// Round 1
// baseline (284.638 us; speedup 1.0000x reference)
//
#include <hip/hip_runtime.h>

constexpr int NN = 100000;   // nodes
constexpr int NE = 1600000;  // edges
constexpr int NF = 64;       // input features
constexpr int NH = 16;       // hidden

// Kernel 1: per node n: p[n,:] = x[n,:] @ Wl1 ; agg[n,:] = x[n,:] @ Wr1
// agg is pre-initialized with the lin_r term so the edge atomics accumulate on top.
__global__ __launch_bounds__(256)
void k1_node_lin(const float* __restrict__ x,
                 const float* __restrict__ Wl1,
                 const float* __restrict__ Wr1,
                 float* __restrict__ p,
                 float* __restrict__ agg)
{
    __shared__ float sW[2 * NF * NH];   // Wl1 | Wr1, row-major [k][j]
    for (int i = threadIdx.x; i < NF * NH; i += 256) {
        sW[i]           = Wl1[i];
        sW[NF * NH + i] = Wr1[i];
    }
    __syncthreads();

    int n = blockIdx.x * 256 + threadIdx.x;
    if (n >= NN) return;

    float aL[NH], aR[NH];
#pragma unroll
    for (int j = 0; j < NH; ++j) { aL[j] = 0.f; aR[j] = 0.f; }

    const float4* xr = reinterpret_cast<const float4*>(x + (size_t)n * NF);
#pragma unroll
    for (int k4 = 0; k4 < NF / 4; ++k4) {
        float4 v = xr[k4];
        float xs[4] = {v.x, v.y, v.z, v.w};
#pragma unroll
        for (int t = 0; t < 4; ++t) {
            const float* wl = &sW[(k4 * 4 + t) * NH];          // broadcast LDS reads
            const float* wr = &sW[NF * NH + (k4 * 4 + t) * NH];
#pragma unroll
            for (int j = 0; j < NH; ++j) {
                aL[j] = fmaf(xs[t], wl[j], aL[j]);
                aR[j] = fmaf(xs[t], wr[j], aR[j]);
            }
        }
    }

    float4* pp = reinterpret_cast<float4*>(p   + (size_t)n * NH);
    float4* ap = reinterpret_cast<float4*>(agg + (size_t)n * NH);
#pragma unroll
    for (int j4 = 0; j4 < NH / 4; ++j4) {
        pp[j4] = make_float4(aL[j4*4], aL[j4*4+1], aL[j4*4+2], aL[j4*4+3]);
        ap[j4] = make_float4(aR[j4*4], aR[j4*4+1], aR[j4*4+2], aR[j4*4+3]);
    }
}

// Kernel 2: 16 lanes per edge; lane k does agg[dst*16+k] += p[src*16+k] if mask.
__global__ __launch_bounds__(256)
void k2_edge_scatter(const int* __restrict__ ei,     // [2, NE]: src row, dst row
                     const float* __restrict__ As,   // [2, NE]
                     const float* __restrict__ ws,   // [2]
                     const float* __restrict__ p,
                     float* __restrict__ agg)
{
    long long t = (long long)blockIdx.x * 256 + threadIdx.x;
    int e = (int)(t >> 4);
    int k = (int)(t & 15);
    if (e >= NE) return;

    float ewm = ws[0] * As[e] + ws[1] * As[NE + e];
    if (ewm == 0.0f) return;   // mask==0 -> contributes nothing

    int src = ei[e];
    int dst = ei[NE + e];
    float v = p[(size_t)src * NH + k];
    atomicAdd(&agg[(size_t)dst * NH + k], v);
}

// Kernel 3: h = relu(agg + bl1); q[n] = h@Wl2 ; out[n] = h@Wr2 + bl2
__global__ __launch_bounds__(256)
void k3_node_fin(const float* __restrict__ agg,
                 const float* __restrict__ bl1,
                 const float* __restrict__ Wl2,
                 const float* __restrict__ bl2,
                 const float* __restrict__ Wr2,
                 float* __restrict__ q,
                 float* __restrict__ out)
{
    __shared__ float sb[NH], sl[NH], sr[NH];
    if (threadIdx.x < NH) {
        sb[threadIdx.x] = bl1[threadIdx.x];
        sl[threadIdx.x] = Wl2[threadIdx.x];
        sr[threadIdx.x] = Wr2[threadIdx.x];
    }
    __syncthreads();

    int n = blockIdx.x * 256 + threadIdx.x;
    if (n >= NN) return;

    float qq = 0.f, ss = 0.f;
    const float4* ar = reinterpret_cast<const float4*>(agg + (size_t)n * NH);
#pragma unroll
    for (int j4 = 0; j4 < NH / 4; ++j4) {
        float4 a = ar[j4];
        float av[4] = {a.x, a.y, a.z, a.w};
#pragma unroll
        for (int t = 0; t < 4; ++t) {
            int j = j4 * 4 + t;
            float h = av[t] + sb[j];
            h = h > 0.f ? h : 0.f;
            qq = fmaf(h, sl[j], qq);
            ss = fmaf(h, sr[j], ss);
        }
    }
    q[n]   = qq;
    out[n] = ss + bl2[0];
}

// Kernel 4: one thread per edge; out[dst] += q[src] if mask.
__global__ __launch_bounds__(256)
void k4_edge_scalar(const int* __restrict__ ei,
                    const float* __restrict__ As,
                    const float* __restrict__ ws,
                    const float* __restrict__ q,
                    float* __restrict__ out)
{
    int e = blockIdx.x * 256 + threadIdx.x;
    if (e >= NE) return;

    float ewm = ws[0] * As[e] + ws[1] * As[NE + e];
    if (ewm == 0.0f) return;

    int src = ei[e];
    int dst = ei[NE + e];
    atomicAdd(&out[dst], q[src]);
}

extern "C" void kernel_launch(void* const* d_in, const int* in_sizes, int n_in,
                              void* d_out, int out_size, void* d_ws, size_t ws_size,
                              hipStream_t stream)
{
    const float* x   = (const float*)d_in[0];
    const int*   ei  = (const int*)  d_in[1];
    const float* As  = (const float*)d_in[2];
    const float* ws  = (const float*)d_in[3];
    const float* Wl1 = (const float*)d_in[4];
    const float* bl1 = (const float*)d_in[5];
    const float* Wr1 = (const float*)d_in[6];
    const float* Wl2 = (const float*)d_in[7];
    const float* bl2 = (const float*)d_in[8];
    const float* Wr2 = (const float*)d_in[9];
    float* out = (float*)d_out;

    float* p   = (float*)d_ws;                // NN*NH floats
    float* agg = p   + (size_t)NN * NH;       // NN*NH floats
    float* q   = agg + (size_t)NN * NH;       // NN floats
    // total ws use: (2*16+1)*100000*4 B ~= 13.2 MB

    k1_node_lin<<<(NN + 255) / 256, 256, 0, stream>>>(x, Wl1, Wr1, p, agg);

    long long t2 = (long long)NE * NH;
    k2_edge_scatter<<<(int)((t2 + 255) / 256), 256, 0, stream>>>(ei, As, ws, p, agg);

    k3_node_fin<<<(NN + 255) / 256, 256, 0, stream>>>(agg, bl1, Wl2, bl2, Wr2, q, out);

    k4_edge_scalar<<<(NE + 255) / 256, 256, 0, stream>>>(ei, As, ws, q, out);
}